// Round 4
// baseline (7926.427 us; speedup 1.0000x reference)
//
#include <hip/hip_runtime.h>
#include <hip/hip_fp16.h>
#include <stdint.h>

// Problem constants (NamedEntityRecognitionModel)
#define TAGS  32
#define EMB   256
#define HID   512
#define HSZ   256        // per-direction hidden
#define G4H   1024       // 4*HSZ
#define BATCH 64
#define TLEN  512

typedef _Float16 half8  __attribute__((ext_vector_type(8)));
typedef _Float16 half2v __attribute__((ext_vector_type(2)));
typedef float    f32x4  __attribute__((ext_vector_type(4)));
typedef unsigned long long u64x2 __attribute__((ext_vector_type(2)));

#if defined(__has_builtin)
#if __has_builtin(__builtin_amdgcn_fdot2)
#define HAVE_FDOT2 1
#endif
#endif

__device__ __forceinline__ float fdot2f(unsigned a, unsigned b, float c) {
    half2v ha = __builtin_bit_cast(half2v, a);
    half2v hb = __builtin_bit_cast(half2v, b);
#ifdef HAVE_FDOT2
    return __builtin_amdgcn_fdot2(ha, hb, c, false);
#else
    return c + (float)ha[0]*(float)hb[0] + (float)ha[1]*(float)hb[1];
#endif
}
__device__ __forceinline__ float sigmoid_f(float x){ return 1.0f/(1.0f+__expf(-x)); }
__device__ __forceinline__ float tanh_f(float x){ return 1.0f - 2.0f/(__expf(2.0f*x)+1.0f); }

// agent-coherent (cross-XCD, L3-level) accesses: relaxed atomics, no fences
__device__ __forceinline__ half8 load16_agent(const __half* p) {
    const unsigned long long* q = (const unsigned long long*)p;
    u64x2 v;
    v[0] = __hip_atomic_load(q,     __ATOMIC_RELAXED, __HIP_MEMORY_SCOPE_AGENT);
    v[1] = __hip_atomic_load(q + 1, __ATOMIC_RELAXED, __HIP_MEMORY_SCOPE_AGENT);
    return __builtin_bit_cast(half8, v);
}
__device__ __forceinline__ void store8_agent(__half* p, unsigned long long v) {
    __hip_atomic_store((unsigned long long*)p, v, __ATOMIC_RELAXED, __HIP_MEMORY_SCOPE_AGENT);
}

// ---------------------------------------------------------------------------
// K1: xWT[dir][t][n][b] = embed[X[b][t]] . Wi[n] + bias[n]  (f16 out, transposed)
// grid (512 t, 16 ntiles, 2 dir), block 256. fp32 LDS-tiled GEMM + LDS transpose.
// ---------------------------------------------------------------------------
__global__ __launch_bounds__(256)
void gemm_xwt_kernel(const int* __restrict__ X, const float* __restrict__ embed,
                     const float* __restrict__ WiF, const float* __restrict__ bF,
                     const float* __restrict__ WiB, const float* __restrict__ bB,
                     __half* __restrict__ xWT) {
    __shared__ float As[64][17];
    __shared__ float Bs[64][17];
    __shared__ ushort tr[64][72];         // [n_local][b], 144B row stride (16B aligned)

    const int tid = threadIdx.x;
    const int t   = blockIdx.x;           // 0..511
    const int n0  = blockIdx.y * 64;      // 0..960
    const int dir = blockIdx.z;
    const float* Wi   = dir ? WiB : WiF;
    const float* bias = dir ? bB  : bF;

    const int tx = tid & 15, ty = tid >> 4;
    const int lrow = tid >> 2;            // 0..63: batch (A) / n-row (B)
    const int lk   = (tid & 3) * 4;
    const int erow = X[lrow * TLEN + t];  // gather: batch lrow, token t

    float acc[4][4] = {};
    for (int k0 = 0; k0 < EMB; k0 += 16) {
        const float4 av = *(const float4*)&embed[(size_t)erow * EMB + k0 + lk];
        const float4 bv = *(const float4*)&Wi[(size_t)(n0 + lrow) * EMB + k0 + lk];
        __syncthreads();
        As[lrow][lk+0]=av.x; As[lrow][lk+1]=av.y; As[lrow][lk+2]=av.z; As[lrow][lk+3]=av.w;
        Bs[lrow][lk+0]=bv.x; Bs[lrow][lk+1]=bv.y; Bs[lrow][lk+2]=bv.z; Bs[lrow][lk+3]=bv.w;
        __syncthreads();
#pragma unroll
        for (int kk = 0; kk < 16; ++kk) {
            float a0=As[ty*4+0][kk], a1=As[ty*4+1][kk], a2=As[ty*4+2][kk], a3=As[ty*4+3][kk];
            float b0=Bs[tx*4+0][kk], b1=Bs[tx*4+1][kk], b2=Bs[tx*4+2][kk], b3=Bs[tx*4+3][kk];
            acc[0][0]+=a0*b0; acc[0][1]+=a0*b1; acc[0][2]+=a0*b2; acc[0][3]+=a0*b3;
            acc[1][0]+=a1*b0; acc[1][1]+=a1*b1; acc[1][2]+=a1*b2; acc[1][3]+=a1*b3;
            acc[2][0]+=a2*b0; acc[2][1]+=a2*b1; acc[2][2]+=a2*b2; acc[2][3]+=a2*b3;
            acc[3][0]+=a3*b0; acc[3][1]+=a3*b1; acc[3][2]+=a3*b2; acc[3][3]+=a3*b3;
        }
    }
    __syncthreads();
#pragma unroll
    for (int i = 0; i < 4; ++i)
#pragma unroll
        for (int jj = 0; jj < 4; ++jj) {
            const int n = tx*4 + jj, b = ty*4 + i;
            tr[n][b] = __half_as_ushort(__float2half(acc[i][jj] + bias[n0 + n]));
        }
    __syncthreads();
    __half* dst = xWT + (((size_t)dir * TLEN + t) * G4H + n0) * BATCH;
#pragma unroll
    for (int q = 0; q < 2; ++q) {
        const int sid = tid + q*256;
        const int row = sid >> 3, seg = sid & 7;
        const uint4 v = *(const uint4*)&tr[row][seg*8];
        *(uint4*)(dst + (size_t)row * BATCH + seg*8) = v;
    }
}

// ---------------------------------------------------------------------------
// K2: persistent bidirectional LSTM. Wh resident in VGPRs (B-frags loop-
// invariant). grid = 8 blocks (slice s 0..3, dir 0..1), block 256 (4 waves).
// Cross-block h exchange via agent-scope relaxed atomics (L3-coherent, no
// cache-maintenance fences) + generation flags.
// ---------------------------------------------------------------------------
__global__ __launch_bounds__(256, 1)
void lstm_kernel(const __half* __restrict__ xWT,
                 const float* __restrict__ WhF, const float* __restrict__ WhB,
                 __half* __restrict__ hist, int* __restrict__ flags) {
    const int s   = blockIdx.x & 3;
    const int dir = blockIdx.x >> 2;
    const int tid = threadIdx.x;
    const int lane = tid & 63;
    const int w    = tid >> 6;        // wave 0..3: units [64s+16w, +16)
    const int l15  = lane & 15;
    const int lp   = lane >> 4;       // 0..3

    __shared__ ushort hstage[64][68];   // [b][u_local] transpose bounce, 8704 B

    const float* Wh = dir ? WhB : WhF;

    // ---- load Wh B-fragments into registers (loop-invariant) ----
    // B-frag for 16x16x32 f16: lane holds col n = l15 (unit), k = lp*8..+8
    half8 wbf[4][8];
#pragma unroll
    for (int g = 0; g < 4; ++g) {
        const int grow = g * 256 + s * 64 + w * 16 + l15;   // global gate row
        const float* src = Wh + (size_t)grow * HSZ;
#pragma unroll
        for (int k0 = 0; k0 < 8; ++k0) {
            const float4 x0 = *(const float4*)(src + k0 * 32 + lp * 8);
            const float4 x1 = *(const float4*)(src + k0 * 32 + lp * 8 + 4);
            half8 hv;
            hv[0]=(_Float16)x0.x; hv[1]=(_Float16)x0.y; hv[2]=(_Float16)x0.z; hv[3]=(_Float16)x0.w;
            hv[4]=(_Float16)x1.x; hv[5]=(_Float16)x1.y; hv[6]=(_Float16)x1.z; hv[7]=(_Float16)x1.w;
            wbf[g][k0] = hv;
        }
    }

    __half* histD = hist + (size_t)dir * TLEN * BATCH * HSZ;
    const int ubase = s * 64 + w * 16 + l15;   // unit owned by this lane

    f32x4 acc[4][4];       // [gate g][m-tile]
    float c[16];
#pragma unroll
    for (int i = 0; i < 16; ++i) c[i] = 0.0f;
    uint2 xwp[4][4];       // prefetched xWT for current t

    const __half* xwD = xWT + (size_t)dir * TLEN * G4H * BATCH;
#define PREFETCH_XW(T)                                                          \
    {                                                                           \
        const __half* p = xwD + (size_t)(T) * G4H * BATCH;                      \
        _Pragma("unroll")                                                       \
        for (int g = 0; g < 4; ++g) {                                           \
            const __half* pg = p + (size_t)(g * 256 + ubase) * BATCH + lp * 4;  \
            _Pragma("unroll")                                                   \
            for (int m = 0; m < 4; ++m)                                         \
                xwp[g][m] = *(const uint2*)(pg + m * 16);                       \
        }                                                                       \
    }

    PREFETCH_XW(dir ? (TLEN - 1) : 0);

    for (int ts = 0; ts < TLEN; ++ts) {
        const int t     = dir ? (TLEN - 1 - ts) : ts;
        const int tprev = dir ? (t + 1) : (t - 1);

        // acc <- xW(t)
#pragma unroll
        for (int g = 0; g < 4; ++g)
#pragma unroll
            for (int m = 0; m < 4; ++m) {
                const half2v lo = __builtin_bit_cast(half2v, xwp[g][m].x);
                const half2v hi = __builtin_bit_cast(half2v, xwp[g][m].y);
                f32x4 a; a[0]=(float)lo[0]; a[1]=(float)lo[1]; a[2]=(float)hi[0]; a[3]=(float)hi[1];
                acc[g][m] = a;
            }

        if (ts > 0) {
            // wait for all 4 slices to publish h(tprev)
            if (tid < 4 && tid != s) {
                const int* fp = &flags[dir * 4 + tid];
                while (__hip_atomic_load(fp, __ATOMIC_RELAXED,
                                         __HIP_MEMORY_SCOPE_AGENT) < ts) { }
            }
            __syncthreads();

            const __half* hp = histD + (size_t)tprev * (BATCH * HSZ);
            half8 af[4];
#pragma unroll
            for (int m = 0; m < 4; ++m)
                af[m] = load16_agent(hp + (m * 16 + l15) * HSZ + lp * 8);
#pragma unroll
            for (int k0 = 0; k0 < 8; ++k0) {
                half8 an[4];
                if (k0 < 7) {
#pragma unroll
                    for (int m = 0; m < 4; ++m)
                        an[m] = load16_agent(hp + (m*16 + l15) * HSZ + lp*8 + 32*(k0+1));
                }
#pragma unroll
                for (int g = 0; g < 4; ++g)
#pragma unroll
                    for (int m = 0; m < 4; ++m)
                        acc[g][m] = __builtin_amdgcn_mfma_f32_16x16x32_f16(af[m], wbf[g][k0], acc[g][m], 0, 0, 0);
                if (k0 < 7) {
#pragma unroll
                    for (int m = 0; m < 4; ++m) af[m] = an[m];
                }
            }
        }

        // cell update -> LDS transpose bounce
#pragma unroll
        for (int m = 0; m < 4; ++m)
#pragma unroll
            for (int r = 0; r < 4; ++r) {
                const float ig = sigmoid_f(acc[0][m][r]);
                const float fg = sigmoid_f(acc[1][m][r]);
                const float gg = tanh_f   (acc[2][m][r]);
                const float og = sigmoid_f(acc[3][m][r]);
                float cc = c[m*4 + r];
                cc = fg * cc + ig * gg;
                c[m*4 + r] = cc;
                const float hv = og * tanh_f(cc);
                hstage[m*16 + lp*4 + r][w*16 + l15] = __half_as_ushort(__float2half(hv));
            }
        __syncthreads();

        // coalesced coherent publish of own 64-unit slice (8 KB)
        {
            const int rb = tid >> 2, rq = tid & 3;
            __half* hout = histD + (size_t)t * (BATCH * HSZ) + (size_t)rb * HSZ + s * 64 + rq * 16;
            const ushort* hrow = &hstage[rb][rq * 16];
#pragma unroll
            for (int q = 0; q < 4; ++q) {
                const unsigned long long v = *(const unsigned long long*)(hrow + q * 4);
                store8_agent(hout + q * 4, v);
            }
        }
        asm volatile("s_waitcnt vmcnt(0)" ::: "memory");   // own stores at coherence point
        __syncthreads();                                    // all threads' stores done
        if (tid == 0)
            __hip_atomic_store(&flags[dir * 4 + s], ts + 1, __ATOMIC_RELAXED,
                               __HIP_MEMORY_SCOPE_AGENT);

        if (ts + 1 < TLEN) PREFETCH_XW(dir ? (t - 1) : (t + 1));
    }
#undef PREFETCH_XW
}

// ---------------------------------------------------------------------------
// K3: emissions em[b][t][k] = hf(t,b,:).fcW[k,0:256] + hb(t,b,:).fcW[k,256:512]
// grid = 64b x 8 tchunks = 512 blocks, block 256.
// ---------------------------------------------------------------------------
__global__ __launch_bounds__(256)
void em_kernel(const __half* __restrict__ hist, const float* __restrict__ fcW,
               float* __restrict__ em) {
    const int b   = blockIdx.x >> 3;
    const int t0  = (blockIdx.x & 7) * 64;
    const int tid = threadIdx.x;

    __shared__ ushort hf[64][264];
    __shared__ ushort hb[64][264];
    __shared__ ushort fcs[32][520];

    for (int i = tid; i < 32 * 512; i += 256) {
        const int k = i >> 9, j = i & 511;
        fcs[k][j] = __half_as_ushort(__float2half(fcW[(size_t)k * HID + j]));
    }
    const __half* hfp = hist;
    const __half* hbp = hist + (size_t)TLEN * BATCH * HSZ;
    for (int i = tid; i < 64 * 32; i += 256) {
        const int row = i >> 5, seg = i & 31;
        const uint4 vf = *(const uint4*)(hfp + ((size_t)(t0+row) * BATCH + b) * HSZ + seg*8);
        const uint4 vb = *(const uint4*)(hbp + ((size_t)(t0+row) * BATCH + b) * HSZ + seg*8);
        *(uint4*)&hf[row][seg*8] = vf;
        *(uint4*)&hb[row][seg*8] = vb;
    }
    __syncthreads();

    const int tok = tid >> 2;     // 0..63
    const int kq  = tid & 3;      // k = kq*8 + kk
    float s[8] = {0,0,0,0,0,0,0,0};
    for (int j2 = 0; j2 < 128; ++j2) {
        const unsigned hfv = *(const unsigned*)&hf[tok][j2*2];
        const unsigned hbv = *(const unsigned*)&hb[tok][j2*2];
#pragma unroll
        for (int kk = 0; kk < 8; ++kk) {
            const int k = kq*8 + kk;
            s[kk] = fdot2f(hfv, *(const unsigned*)&fcs[k][j2*2], s[kk]);
            s[kk] = fdot2f(hbv, *(const unsigned*)&fcs[k][256 + j2*2], s[kk]);
        }
    }
    float* dst = em + ((size_t)b * TLEN + t0 + tok) * TAGS + kq*8;
#pragma unroll
    for (int kk = 0; kk < 8; ++kk) dst[kk] = s[kk];
}

// ---------------------------------------------------------------------------
// K4: CRF forward + gold score per batch row. grid 64, block 64.
// ---------------------------------------------------------------------------
__global__ void crf_kernel(const float* __restrict__ em, const float* __restrict__ fcb,
                           const float* __restrict__ trans, const float* __restrict__ startv,
                           const float* __restrict__ endv, const int* __restrict__ y,
                           float* __restrict__ partial) {
    const int b   = blockIdx.x;
    const int tid = threadIdx.x;

    __shared__ float alpha_s[TAGS];
    __shared__ float trans_s[TAGS][TAGS + 1];

    for (int i = tid; i < TAGS * TAGS; i += 64)
        trans_s[i >> 5][i & 31] = trans[i];

    const float* e = em + (size_t)b * TLEN * TAGS;

    if (tid < TAGS)
        alpha_s[tid] = startv[tid] + e[tid] + fcb[tid];
    __syncthreads();

    for (int t = 1; t < TLEN; ++t) {
        float anew = 0.0f;
        if (tid < TAGS) {
            float mx = -3.0e38f;
#pragma unroll
            for (int k2 = 0; k2 < TAGS; ++k2)
                mx = fmaxf(mx, alpha_s[k2] + trans_s[k2][tid]);
            float sm = 0.0f;
#pragma unroll
            for (int k2 = 0; k2 < TAGS; ++k2)
                sm += __expf(alpha_s[k2] + trans_s[k2][tid] - mx);
            anew = mx + __logf(sm) + e[t * TAGS + tid] + fcb[tid];
        }
        __syncthreads();
        if (tid < TAGS) alpha_s[tid] = anew;
        __syncthreads();
    }

    float v = (tid < TAGS) ? (alpha_s[tid] + endv[tid]) : -1.0e30f;
    float mx = v;
#pragma unroll
    for (int off = 32; off; off >>= 1) mx = fmaxf(mx, __shfl_xor(mx, off, 64));
    float ex = __expf(v - mx);
#pragma unroll
    for (int off = 32; off; off >>= 1) ex += __shfl_xor(ex, off, 64);
    const float logZ = mx + __logf(ex);

    const int* yb = y + (size_t)b * TLEN;
    float gsum = 0.0f;
    for (int t = tid; t < TLEN; t += 64) {
        const int yt = yb[t];
        gsum += e[t * TAGS + yt] + fcb[yt];
    }
    for (int t = tid; t < TLEN - 1; t += 64)
        gsum += trans[yb[t] * TAGS + yb[t + 1]];
#pragma unroll
    for (int off = 32; off; off >>= 1) gsum += __shfl_xor(gsum, off, 64);

    if (tid == 0) {
        const float num = startv[yb[0]] + gsum + endv[yb[TLEN - 1]];
        partial[b] = logZ - num;
    }
}

// ---------------------------------------------------------------------------
// K5: final mean
// ---------------------------------------------------------------------------
__global__ void reduce_kernel(const float* __restrict__ partial, float* __restrict__ out) {
    float v = partial[threadIdx.x];
#pragma unroll
    for (int off = 32; off; off >>= 1) v += __shfl_xor(v, off, 64);
    if (threadIdx.x == 0) out[0] = v * (1.0f / BATCH);
}

// ---------------------------------------------------------------------------
extern "C" void kernel_launch(void* const* d_in, const int* in_sizes, int n_in,
                              void* d_out, int out_size, void* d_ws, size_t ws_size,
                              hipStream_t stream) {
    (void)in_sizes; (void)n_in; (void)out_size; (void)ws_size;

    const int*   X      = (const int*)  d_in[0];
    const int*   y      = (const int*)  d_in[1];
    const float* embed  = (const float*)d_in[2];
    const float* Wi_f   = (const float*)d_in[3];
    const float* Wh_f   = (const float*)d_in[4];
    const float* b_f    = (const float*)d_in[5];
    const float* Wi_b   = (const float*)d_in[6];
    const float* Wh_b   = (const float*)d_in[7];
    const float* b_b    = (const float*)d_in[8];
    const float* fcW    = (const float*)d_in[9];
    const float* fcb    = (const float*)d_in[10];
    const float* trans  = (const float*)d_in[11];
    const float* startv = (const float*)d_in[12];
    const float* endv   = (const float*)d_in[13];
    float* out = (float*)d_out;

    // workspace layout
    char* ws = (char*)d_ws;
    __half* xWT  = (__half*)(ws);                    // [2][512][1024][64] f16 = 134217728 B
    __half* hist = (__half*)(ws + 134217728);        // [2][512][64][256] f16 =  33554432 B
    float*  em   = (float*) (ws + 167772160);        // [64][512][32] f32     =   4194304 B
    float*  prt  = (float*) (ws + 171966464);        //                            256 B
    int*    flg  = (int*)   (ws + 171966720);        // [2][4] generation flags     64 B

    hipMemsetAsync(flg, 0, 64, stream);

    dim3 ggrid(TLEN, G4H / 64, 2);
    gemm_xwt_kernel<<<ggrid, 256, 0, stream>>>(X, embed, Wi_f, b_f, Wi_b, b_b, xWT);

    lstm_kernel<<<8, 256, 0, stream>>>(xWT, Wh_f, Wh_b, hist, flg);

    em_kernel<<<BATCH * 8, 256, 0, stream>>>(hist, fcW, em);

    crf_kernel<<<BATCH, 64, 0, stream>>>(em, fcb, trans, startv, endv, y, prt);

    reduce_kernel<<<1, 64, 0, stream>>>(prt, out);
}

// Round 6
// 7115.273 us; speedup vs baseline: 1.1140x; 1.1140x over previous
//
#include <hip/hip_runtime.h>
#include <hip/hip_fp16.h>
#include <stdint.h>

// Problem constants (NamedEntityRecognitionModel)
#define TAGS  32
#define EMB   256
#define HID   512
#define HSZ   256        // per-direction hidden
#define G4H   1024       // 4*HSZ
#define BATCH 64
#define TLEN  512

typedef _Float16 half8  __attribute__((ext_vector_type(8)));
typedef _Float16 half2v __attribute__((ext_vector_type(2)));
typedef float    f32x4  __attribute__((ext_vector_type(4)));
typedef unsigned int u32x2 __attribute__((ext_vector_type(2)));
typedef unsigned int u32x4 __attribute__((ext_vector_type(4)));

#if defined(__has_builtin)
#if __has_builtin(__builtin_amdgcn_fdot2)
#define HAVE_FDOT2 1
#endif
#endif

__device__ __forceinline__ float fdot2f(unsigned a, unsigned b, float c) {
    half2v ha = __builtin_bit_cast(half2v, a);
    half2v hb = __builtin_bit_cast(half2v, b);
#ifdef HAVE_FDOT2
    return __builtin_amdgcn_fdot2(ha, hb, c, false);
#else
    return c + (float)ha[0]*(float)hb[0] + (float)ha[1]*(float)hb[1];
#endif
}
__device__ __forceinline__ float sigmoid_f(float x){ return 1.0f/(1.0f+__expf(-x)); }
__device__ __forceinline__ float tanh_f(float x){ return 1.0f - 2.0f/(__expf(2.0f*x)+1.0f); }

// ---------------------------------------------------------------------------
// K0: build the MFMA B-fragment image of Wh (f32 -> f16).
// WhT[dir][w 4][g 4][ng 4][ks 8][lane 64][e 8]:
//   n = g*256 + w*64 + ng*16 + (lane&15), k = ks*32 + (lane>>4)*8 + e
// so the LSTM hot loop's B loads are perfectly coalesced dwordx4.
// ---------------------------------------------------------------------------
__global__ __launch_bounds__(256)
void whimg_kernel(const float* __restrict__ WhF, const float* __restrict__ WhB,
                  __half* __restrict__ WhT) {
    const int slot = blockIdx.x * 256 + threadIdx.x;   // 0..65535 (2 dirs x 32768)
    const int dir = slot >> 15, r = slot & 32767;
    const int lane = r & 63;
    const int ks = (r >> 6) & 7;
    const int ng = (r >> 9) & 3;
    const int g  = (r >> 11) & 3;
    const int w  = (r >> 13) & 3;
    const int n = g * 256 + w * 64 + ng * 16 + (lane & 15);
    const int k = ks * 32 + (lane >> 4) * 8;
    const float* src = (dir ? WhB : WhF) + (size_t)n * HSZ + k;
    half8 hv;
#pragma unroll
    for (int e = 0; e < 8; ++e) hv[e] = (_Float16)src[e];
    *(half8*)(WhT + (size_t)slot * 8) = hv;
}

// ---------------------------------------------------------------------------
// K1: xWT[dir][bg][t][n 1024][16 b] = embed[X[b][t]] . Wi[n] + bias[n]  (f16)
// grid (512 t, 16 ntiles, 2 dir), block 256. fp32 LDS-tiled GEMM + transpose.
// ---------------------------------------------------------------------------
__global__ __launch_bounds__(256)
void gemm_xwt_kernel(const int* __restrict__ X, const float* __restrict__ embed,
                     const float* __restrict__ WiF, const float* __restrict__ bF,
                     const float* __restrict__ WiB, const float* __restrict__ bB,
                     __half* __restrict__ xWT) {
    __shared__ float As[64][17];
    __shared__ float Bs[64][17];
    __shared__ ushort tr[64][72];         // [n_local][b]

    const int tid = threadIdx.x;
    const int t   = blockIdx.x;           // 0..511
    const int n0  = blockIdx.y * 64;      // 0..960
    const int dir = blockIdx.z;
    const float* Wi   = dir ? WiB : WiF;
    const float* bias = dir ? bB  : bF;

    const int tx = tid & 15, ty = tid >> 4;
    const int lrow = tid >> 2;            // 0..63: batch (A) / n-row (B)
    const int lk   = (tid & 3) * 4;
    const int erow = X[lrow * TLEN + t];  // gather: batch lrow, token t

    float acc[4][4] = {};
    for (int k0 = 0; k0 < EMB; k0 += 16) {
        const float4 av = *(const float4*)&embed[(size_t)erow * EMB + k0 + lk];
        const float4 bv = *(const float4*)&Wi[(size_t)(n0 + lrow) * EMB + k0 + lk];
        __syncthreads();
        As[lrow][lk+0]=av.x; As[lrow][lk+1]=av.y; As[lrow][lk+2]=av.z; As[lrow][lk+3]=av.w;
        Bs[lrow][lk+0]=bv.x; Bs[lrow][lk+1]=bv.y; Bs[lrow][lk+2]=bv.z; Bs[lrow][lk+3]=bv.w;
        __syncthreads();
#pragma unroll
        for (int kk = 0; kk < 16; ++kk) {
            float a0=As[ty*4+0][kk], a1=As[ty*4+1][kk], a2=As[ty*4+2][kk], a3=As[ty*4+3][kk];
            float b0=Bs[tx*4+0][kk], b1=Bs[tx*4+1][kk], b2=Bs[tx*4+2][kk], b3=Bs[tx*4+3][kk];
            acc[0][0]+=a0*b0; acc[0][1]+=a0*b1; acc[0][2]+=a0*b2; acc[0][3]+=a0*b3;
            acc[1][0]+=a1*b0; acc[1][1]+=a1*b1; acc[1][2]+=a1*b2; acc[1][3]+=a1*b3;
            acc[2][0]+=a2*b0; acc[2][1]+=a2*b1; acc[2][2]+=a2*b2; acc[2][3]+=a2*b3;
            acc[3][0]+=a3*b0; acc[3][1]+=a3*b1; acc[3][2]+=a3*b2; acc[3][3]+=a3*b3;
        }
    }
    __syncthreads();
#pragma unroll
    for (int i = 0; i < 4; ++i)
#pragma unroll
        for (int jj = 0; jj < 4; ++jj) {
            const int n = tx*4 + jj, b = ty*4 + i;
            tr[n][b] = __half_as_ushort(__float2half(acc[i][jj] + bias[n0 + n]));
        }
    __syncthreads();
#pragma unroll
    for (int q = 0; q < 2; ++q) {
        const int sid = tid + q * 256;
        const int row = sid >> 3, seg = sid & 7;     // row = n_local, seg = b-octet
        const int bgD = seg >> 1, bo = (seg & 1) * 8;
        const uint4 v = *(const uint4*)&tr[row][seg * 8];
        __half* dst = xWT + ((size_t)((dir * 4 + bgD) * TLEN + t)) * (G4H * 16)
                    + (size_t)(n0 + row) * 16 + bo;
        *(uint4*)dst = v;
    }
}

// ---------------------------------------------------------------------------
// K2: batch-split LSTM, ZERO inter-block sync. grid (4 bg, 2 dir), block 256.
// Each block: 16 batches, full Wh streamed from L2 each step straight into
// MFMA B-frags (double-buffered). h kept in swizzled LDS; c in VGPRs.
// Wave w owns units [64w, 64w+64) (all 4 gates for those units).
// ---------------------------------------------------------------------------
__global__ __launch_bounds__(256, 1)
void lstm_kernel(const __half* __restrict__ xWT, const __half* __restrict__ WhT,
                 __half* __restrict__ hist) {
    const int bg  = blockIdx.x;       // 0..3
    const int dir = blockIdx.y;       // 0..1
    const int tid = threadIdx.x;
    const int lane = tid & 63;
    const int w    = tid >> 6;        // wave 0..3
    const int l15  = lane & 15;
    const int lp   = lane >> 4;

    __shared__ ushort hls[16 * 256];  // h[b 16][u 256] f16, XOR-swizzled

    const uint4*  wp  = (const uint4*)(WhT + (size_t)(dir * 4 + w) * 65536);
    const __half* xwD = xWT + (size_t)(dir * 4 + bg) * ((size_t)TLEN * G4H * 16);
    __half*       hD  = hist + (size_t)(dir * BATCH + bg * 16) * TLEN * HSZ;

    for (int i = tid; i < 4096; i += 256) hls[i] = 0;

    float c[16];
#pragma unroll
    for (int i = 0; i < 16; ++i) c[i] = 0.0f;

    int nidx[16];                     // n-col of group gg for this lane
#pragma unroll
    for (int gg = 0; gg < 16; ++gg)
        nidx[gg] = (gg >> 2) * 256 + w * 64 + (gg & 3) * 16 + l15;

    f32x4 acc[16];
    u32x2 xwc[16], xwn[16];
    {
        const int t0 = dir ? (TLEN - 1) : 0;
        const __half* p = xwD + (size_t)t0 * (G4H * 16);
#pragma unroll
        for (int gg = 0; gg < 16; ++gg)
            xwc[gg] = __builtin_nontemporal_load((const u32x2*)(p + nidx[gg] * 16 + lp * 4));
    }
    __syncthreads();

    for (int ts = 0; ts < TLEN; ++ts) {
        const int t = dir ? (TLEN - 1 - ts) : ts;

        // A-frags: h(t-1) from LDS (zeros at ts==0)
        uint4 afr[8];
#pragma unroll
        for (int ks = 0; ks < 8; ++ks)
            afr[ks] = *(const uint4*)((const char*)hls +
                        ((l15 * 512 + ks * 64 + lp * 16) ^ ((l15 & 7) << 4)));

        // acc <- xW(t)
#pragma unroll
        for (int gg = 0; gg < 16; ++gg) {
            const half2v lo = __builtin_bit_cast(half2v, xwc[gg].x);
            const half2v hi = __builtin_bit_cast(half2v, xwc[gg].y);
            f32x4 a; a[0]=(float)lo[0]; a[1]=(float)lo[1]; a[2]=(float)hi[0]; a[3]=(float)hi[1];
            acc[gg] = a;
        }

        // B stream from L2 + MFMA, double-buffered one group (8 KB/wave) ahead
        uint4 bfr[2][8];
#pragma unroll
        for (int ks = 0; ks < 8; ++ks)
            bfr[0][ks] = wp[ks * 64 + lane];
#pragma unroll
        for (int gg = 0; gg < 16; ++gg) {
            if (gg < 15) {
#pragma unroll
                for (int ks = 0; ks < 8; ++ks)
                    bfr[(gg + 1) & 1][ks] = wp[((gg + 1) * 8 + ks) * 64 + lane];
            }
#pragma unroll
            for (int ks = 0; ks < 8; ++ks)
                acc[gg] = __builtin_amdgcn_mfma_f32_16x16x32_f16(
                    __builtin_bit_cast(half8, afr[ks]),
                    __builtin_bit_cast(half8, bfr[gg & 1][ks]), acc[gg], 0, 0, 0);
        }

        // prefetch xW(t_next) — nontemporal, read-once stream
        {
            const int tn = dir ? (t > 0 ? t - 1 : 0) : (t < TLEN - 1 ? t + 1 : TLEN - 1);
            const __half* p = xwD + (size_t)tn * (G4H * 16);
#pragma unroll
            for (int gg = 0; gg < 16; ++gg)
                xwn[gg] = __builtin_nontemporal_load((const u32x2*)(p + nidx[gg] * 16 + lp * 4));
        }

        __syncthreads();   // all waves done reading h(t-1)

        // cell update + h(t) LDS write
#pragma unroll
        for (int ng = 0; ng < 4; ++ng) {
            const int u = w * 64 + ng * 16 + l15;
#pragma unroll
            for (int rr = 0; rr < 4; ++rr) {
                const float ig = sigmoid_f(acc[     ng][rr]);
                const float fg = sigmoid_f(acc[ 4 + ng][rr]);
                const float gv = tanh_f   (acc[ 8 + ng][rr]);
                const float og = sigmoid_f(acc[12 + ng][rr]);
                float cc = c[ng * 4 + rr];
                cc = fg * cc + ig * gv;
                c[ng * 4 + rr] = cc;
                const float hv = og * tanh_f(cc);
                const int b = lp * 4 + rr;
                *(ushort*)((char*)hls + ((b * 512 + u * 2) ^ ((b & 7) << 4))) =
                    __half_as_ushort(__float2half(hv));
            }
        }
        __syncthreads();   // h(t) complete

        // spill h(t) -> hist (nontemporal, for emissions kernel)
        {
            const int bl = tid >> 4, us = tid & 15;
            const char* s0 = (const char*)hls;
            const uint4 v0 = *(const uint4*)(s0 + ((bl * 512 + us * 32)      ^ ((bl & 7) << 4)));
            const uint4 v1 = *(const uint4*)(s0 + ((bl * 512 + us * 32 + 16) ^ ((bl & 7) << 4)));
            __half* dp = hD + ((size_t)bl * TLEN + t) * HSZ + us * 16;
            __builtin_nontemporal_store(__builtin_bit_cast(u32x4, v0), (u32x4*)dp);
            __builtin_nontemporal_store(__builtin_bit_cast(u32x4, v1), (u32x4*)(dp + 8));
        }

#pragma unroll
        for (int gg = 0; gg < 16; ++gg) xwc[gg] = xwn[gg];
    }
}

// ---------------------------------------------------------------------------
// K3: emissions em[b][t][k] = hf(b,t,:).fcW[k,0:256] + hb(b,t,:).fcW[k,256:512]
// hist layout: [dir][b][t][u]. grid = 64b x 8 tchunks, block 256.
// ---------------------------------------------------------------------------
__global__ __launch_bounds__(256)
void em_kernel(const __half* __restrict__ hist, const float* __restrict__ fcW,
               float* __restrict__ em) {
    const int b   = blockIdx.x >> 3;
    const int t0  = (blockIdx.x & 7) * 64;
    const int tid = threadIdx.x;

    __shared__ ushort hf[64][264];
    __shared__ ushort hb[64][264];
    __shared__ ushort fcs[32][520];

    for (int i = tid; i < 32 * 512; i += 256) {
        const int k = i >> 9, j = i & 511;
        fcs[k][j] = __half_as_ushort(__float2half(fcW[(size_t)k * HID + j]));
    }
    const __half* hfp = hist;
    const __half* hbp = hist + (size_t)BATCH * TLEN * HSZ;
    for (int i = tid; i < 64 * 32; i += 256) {
        const int row = i >> 5, seg = i & 31;
        const uint4 vf = *(const uint4*)(hfp + ((size_t)b * TLEN + t0 + row) * HSZ + seg*8);
        const uint4 vb = *(const uint4*)(hbp + ((size_t)b * TLEN + t0 + row) * HSZ + seg*8);
        *(uint4*)&hf[row][seg*8] = vf;
        *(uint4*)&hb[row][seg*8] = vb;
    }
    __syncthreads();

    const int tok = tid >> 2;     // 0..63
    const int kq  = tid & 3;      // k = kq*8 + kk
    float s[8] = {0,0,0,0,0,0,0,0};
    for (int j2 = 0; j2 < 128; ++j2) {
        const unsigned hfv = *(const unsigned*)&hf[tok][j2*2];
        const unsigned hbv = *(const unsigned*)&hb[tok][j2*2];
#pragma unroll
        for (int kk = 0; kk < 8; ++kk) {
            const int k = kq*8 + kk;
            s[kk] = fdot2f(hfv, *(const unsigned*)&fcs[k][j2*2], s[kk]);
            s[kk] = fdot2f(hbv, *(const unsigned*)&fcs[k][256 + j2*2], s[kk]);
        }
    }
    float* dst = em + ((size_t)b * TLEN + t0 + tok) * TAGS + kq*8;
#pragma unroll
    for (int kk = 0; kk < 8; ++kk) dst[kk] = s[kk];
}

// ---------------------------------------------------------------------------
// K4: CRF forward + gold score per batch row. grid 64, block 64.
// ---------------------------------------------------------------------------
__global__ void crf_kernel(const float* __restrict__ em, const float* __restrict__ fcb,
                           const float* __restrict__ trans, const float* __restrict__ startv,
                           const float* __restrict__ endv, const int* __restrict__ y,
                           float* __restrict__ partial) {
    const int b   = blockIdx.x;
    const int tid = threadIdx.x;

    __shared__ float alpha_s[TAGS];
    __shared__ float trans_s[TAGS][TAGS + 1];

    for (int i = tid; i < TAGS * TAGS; i += 64)
        trans_s[i >> 5][i & 31] = trans[i];

    const float* e = em + (size_t)b * TLEN * TAGS;

    if (tid < TAGS)
        alpha_s[tid] = startv[tid] + e[tid] + fcb[tid];
    __syncthreads();

    for (int t = 1; t < TLEN; ++t) {
        float anew = 0.0f;
        if (tid < TAGS) {
            float mx = -3.0e38f;
#pragma unroll
            for (int k2 = 0; k2 < TAGS; ++k2)
                mx = fmaxf(mx, alpha_s[k2] + trans_s[k2][tid]);
            float sm = 0.0f;
#pragma unroll
            for (int k2 = 0; k2 < TAGS; ++k2)
                sm += __expf(alpha_s[k2] + trans_s[k2][tid] - mx);
            anew = mx + __logf(sm) + e[t * TAGS + tid] + fcb[tid];
        }
        __syncthreads();
        if (tid < TAGS) alpha_s[tid] = anew;
        __syncthreads();
    }

    float v = (tid < TAGS) ? (alpha_s[tid] + endv[tid]) : -1.0e30f;
    float mx = v;
#pragma unroll
    for (int off = 32; off; off >>= 1) mx = fmaxf(mx, __shfl_xor(mx, off, 64));
    float ex = __expf(v - mx);
#pragma unroll
    for (int off = 32; off; off >>= 1) ex += __shfl_xor(ex, off, 64);
    const float logZ = mx + __logf(ex);

    const int* yb = y + (size_t)b * TLEN;
    float gsum = 0.0f;
    for (int t = tid; t < TLEN; t += 64) {
        const int yt = yb[t];
        gsum += e[t * TAGS + yt] + fcb[yt];
    }
    for (int t = tid; t < TLEN - 1; t += 64)
        gsum += trans[yb[t] * TAGS + yb[t + 1]];
#pragma unroll
    for (int off = 32; off; off >>= 1) gsum += __shfl_xor(gsum, off, 64);

    if (tid == 0) {
        const float num = startv[yb[0]] + gsum + endv[yb[TLEN - 1]];
        partial[b] = logZ - num;
    }
}

// ---------------------------------------------------------------------------
// K5: final mean
// ---------------------------------------------------------------------------
__global__ void reduce_kernel(const float* __restrict__ partial, float* __restrict__ out) {
    float v = partial[threadIdx.x];
#pragma unroll
    for (int off = 32; off; off >>= 1) v += __shfl_xor(v, off, 64);
    if (threadIdx.x == 0) out[0] = v * (1.0f / BATCH);
}

// ---------------------------------------------------------------------------
extern "C" void kernel_launch(void* const* d_in, const int* in_sizes, int n_in,
                              void* d_out, int out_size, void* d_ws, size_t ws_size,
                              hipStream_t stream) {
    (void)in_sizes; (void)n_in; (void)out_size; (void)ws_size;

    const int*   X      = (const int*)  d_in[0];
    const int*   y      = (const int*)  d_in[1];
    const float* embed  = (const float*)d_in[2];
    const float* Wi_f   = (const float*)d_in[3];
    const float* Wh_f   = (const float*)d_in[4];
    const float* b_f    = (const float*)d_in[5];
    const float* Wi_b   = (const float*)d_in[6];
    const float* Wh_b   = (const float*)d_in[7];
    const float* b_b    = (const float*)d_in[8];
    const float* fcW    = (const float*)d_in[9];
    const float* fcb    = (const float*)d_in[10];
    const float* trans  = (const float*)d_in[11];
    const float* startv = (const float*)d_in[12];
    const float* endv   = (const float*)d_in[13];
    float* out = (float*)d_out;

    // workspace layout (em aliases xWT: xWT is dead once lstm_kernel finishes)
    char* ws = (char*)d_ws;
    __half* xWT  = (__half*)(ws);                    // [2][4][512][1024][16] f16 = 134217728 B
    float*  em   = (float*) (ws);                    // alias: [64][512][32] f32 = 4194304 B
    __half* hist = (__half*)(ws + 134217728);        // [2][64][512][256] f16 = 33554432 B
    __half* WhT  = (__half*)(ws + 167772160);        // B-frag image, 1048576 B
    float*  prt  = (float*) (ws + 168820736);        // 256 B

    whimg_kernel<<<256, 256, 0, stream>>>(Wh_f, Wh_b, WhT);

    dim3 ggrid(TLEN, G4H / 64, 2);
    gemm_xwt_kernel<<<ggrid, 256, 0, stream>>>(X, embed, Wi_f, b_f, Wi_b, b_b, xWT);

    dim3 lgrid(4, 2);
    lstm_kernel<<<lgrid, 256, 0, stream>>>(xWT, WhT, hist);

    em_kernel<<<BATCH * 8, 256, 0, stream>>>(hist, fcW, em);

    crf_kernel<<<BATCH, 64, 0, stream>>>(em, fcb, trans, startv, endv, y, prt);

    reduce_kernel<<<1, 64, 0, stream>>>(prt, out);
}

// Round 7
// 3193.724 us; speedup vs baseline: 2.4819x; 2.2279x over previous
//
#include <hip/hip_runtime.h>
#include <hip/hip_fp16.h>
#include <hip/hip_fp8.h>
#include <stdint.h>

// Problem constants (NamedEntityRecognitionModel)
#define TAGS  32
#define EMB   256
#define HID   512
#define HSZ   256        // per-direction hidden
#define G4H   1024       // 4*HSZ
#define BATCH 64
#define TLEN  512

typedef _Float16 half8  __attribute__((ext_vector_type(8)));
typedef _Float16 half2v __attribute__((ext_vector_type(2)));
typedef float    f32x4  __attribute__((ext_vector_type(4)));
typedef unsigned int u32x2 __attribute__((ext_vector_type(2)));

#if defined(__has_builtin)
#if __has_builtin(__builtin_amdgcn_fdot2)
#define HAVE_FDOT2 1
#endif
#if __has_builtin(__builtin_amdgcn_cvt_pk_fp8_f32)
#define HAVE_CVTFP8 1
#endif
#endif

__device__ __forceinline__ float fdot2f(unsigned a, unsigned b, float c) {
    half2v ha = __builtin_bit_cast(half2v, a);
    half2v hb = __builtin_bit_cast(half2v, b);
#ifdef HAVE_FDOT2
    return __builtin_amdgcn_fdot2(ha, hb, c, false);
#else
    return c + (float)ha[0]*(float)hb[0] + (float)ha[1]*(float)hb[1];
#endif
}
__device__ __forceinline__ float sigmoid_f(float x){ return 1.0f/(1.0f+__expf(-x)); }
__device__ __forceinline__ float tanh_f(float x){ return 1.0f - 2.0f/(__expf(2.0f*x)+1.0f); }

// float -> OCP e4m3fn byte (HW convert when available)
__device__ __forceinline__ unsigned char to_fp8(float x) {
#ifdef HAVE_CVTFP8
    return (unsigned char)(__builtin_amdgcn_cvt_pk_fp8_f32(x, x, 0, false) & 0xff);
#else
    __hip_fp8_e4m3 q(x);
    return (unsigned char)q.__x;
#endif
}

// ---------------------------------------------------------------------------
// K0: build the fp8 MFMA B-fragment image of Wh, scaled by 8.
// Slot bits: [dir][w 8][gg 8][ks 8][lane 64], 8 bytes per slot:
//   n = (gg>>1)*256 + w*32 + (gg&1)*16 + (lane&15)   (gate g = gg>>1, ng = gg&1)
//   k = ks*32 + (lane>>4)*8 + e
// ---------------------------------------------------------------------------
__global__ __launch_bounds__(256)
void whimg_kernel(const float* __restrict__ WhF, const float* __restrict__ WhB,
                  unsigned long long* __restrict__ WhT8) {
    const int slot = blockIdx.x * 256 + threadIdx.x;   // 0..65535
    const int dir = slot >> 15, r = slot & 32767;
    const int lane = r & 63;
    const int ks = (r >> 6) & 7;
    const int gg = (r >> 9) & 7;
    const int w  = (r >> 12) & 7;
    const int n = (gg >> 1) * 256 + w * 32 + (gg & 1) * 16 + (lane & 15);
    const int k = ks * 32 + (lane >> 4) * 8;
    const float* src = (dir ? WhB : WhF) + (size_t)n * HSZ + k;
    unsigned long long v = 0;
#pragma unroll
    for (int e = 0; e < 8; ++e)
        v |= (unsigned long long)to_fp8(8.0f * src[e]) << (8 * e);
    WhT8[slot] = v;
}

// ---------------------------------------------------------------------------
// K1: xWT[dir][bg][t][n 1024][16 b] = 64*(embed[X[b][t]] . Wi[n] + bias[n])  f16
// grid (512 t, 16 ntiles, 2 dir), block 256. fp32 LDS-tiled GEMM + transpose.
// (the x64 pre-scale matches the fp8 recurrent path: acc = 64*gate_preact)
// ---------------------------------------------------------------------------
__global__ __launch_bounds__(256)
void gemm_xwt_kernel(const int* __restrict__ X, const float* __restrict__ embed,
                     const float* __restrict__ WiF, const float* __restrict__ bF,
                     const float* __restrict__ WiB, const float* __restrict__ bB,
                     __half* __restrict__ xWT) {
    __shared__ float As[64][17];
    __shared__ float Bs[64][17];
    __shared__ ushort tr[64][72];         // [n_local][b]

    const int tid = threadIdx.x;
    const int t   = blockIdx.x;           // 0..511
    const int n0  = blockIdx.y * 64;      // 0..960
    const int dir = blockIdx.z;
    const float* Wi   = dir ? WiB : WiF;
    const float* bias = dir ? bB  : bF;

    const int tx = tid & 15, ty = tid >> 4;
    const int lrow = tid >> 2;            // 0..63: batch (A) / n-row (B)
    const int lk   = (tid & 3) * 4;
    const int erow = X[lrow * TLEN + t];  // gather: batch lrow, token t

    float acc[4][4] = {};
    for (int k0 = 0; k0 < EMB; k0 += 16) {
        const float4 av = *(const float4*)&embed[(size_t)erow * EMB + k0 + lk];
        const float4 bv = *(const float4*)&Wi[(size_t)(n0 + lrow) * EMB + k0 + lk];
        __syncthreads();
        As[lrow][lk+0]=av.x; As[lrow][lk+1]=av.y; As[lrow][lk+2]=av.z; As[lrow][lk+3]=av.w;
        Bs[lrow][lk+0]=bv.x; Bs[lrow][lk+1]=bv.y; Bs[lrow][lk+2]=bv.z; Bs[lrow][lk+3]=bv.w;
        __syncthreads();
#pragma unroll
        for (int kk = 0; kk < 16; ++kk) {
            float a0=As[ty*4+0][kk], a1=As[ty*4+1][kk], a2=As[ty*4+2][kk], a3=As[ty*4+3][kk];
            float b0=Bs[tx*4+0][kk], b1=Bs[tx*4+1][kk], b2=Bs[tx*4+2][kk], b3=Bs[tx*4+3][kk];
            acc[0][0]+=a0*b0; acc[0][1]+=a0*b1; acc[0][2]+=a0*b2; acc[0][3]+=a0*b3;
            acc[1][0]+=a1*b0; acc[1][1]+=a1*b1; acc[1][2]+=a1*b2; acc[1][3]+=a1*b3;
            acc[2][0]+=a2*b0; acc[2][1]+=a2*b1; acc[2][2]+=a2*b2; acc[2][3]+=a2*b3;
            acc[3][0]+=a3*b0; acc[3][1]+=a3*b1; acc[3][2]+=a3*b2; acc[3][3]+=a3*b3;
        }
    }
    __syncthreads();
#pragma unroll
    for (int i = 0; i < 4; ++i)
#pragma unroll
        for (int jj = 0; jj < 4; ++jj) {
            const int n = tx*4 + jj, b = ty*4 + i;
            tr[n][b] = __half_as_ushort(__float2half(64.0f * (acc[i][jj] + bias[n0 + n])));
        }
    __syncthreads();
#pragma unroll
    for (int q = 0; q < 2; ++q) {
        const int sid = tid + q * 256;
        const int row = sid >> 3, seg = sid & 7;     // row = n_local, seg = b-octet
        const int bgD = seg >> 1, bo = (seg & 1) * 8;
        const uint4 v = *(const uint4*)&tr[row][seg * 8];
        __half* dst = xWT + ((size_t)((dir * 4 + bgD) * TLEN + t)) * (G4H * 16)
                    + (size_t)(n0 + row) * 16 + bo;
        *(uint4*)dst = v;
    }
}

// ---------------------------------------------------------------------------
// K2: batch-split LSTM, Wh fp8-resident in VGPRs, zero inter-block sync.
// grid (4 bg, 2 dir), block 512 (8 waves -> 2 waves/SIMD).
// Wave w owns units [32w, 32w+32) x 4 gates; 64 fp8 B-frags live in wbf[8][8].
// h kept in LDS twice: fp8 (x8 scale, MFMA A-side) and f16 (spill to hist).
// acc carries 64*gate_preact (xW pre-scaled, fp8 operands scaled 8x8).
// ---------------------------------------------------------------------------
__global__ __launch_bounds__(512, 2)
void lstm_kernel(const __half* __restrict__ xWT,
                 const unsigned long long* __restrict__ WhT8,
                 __half* __restrict__ hist) {
    const int bg  = blockIdx.x;       // 0..3
    const int dir = blockIdx.y;       // 0..1
    const int tid = threadIdx.x;
    const int lane = tid & 63;
    const int w    = tid >> 6;        // wave 0..7
    const int l15  = lane & 15;
    const int lp   = lane >> 4;

    __shared__ unsigned char h8[16 * 256];   // fp8(8*h): [b][u], XOR-swizzled, 4 KB
    __shared__ ushort hstage[16 * 256];      // f16 h:    [b][u], XOR-swizzled, 8 KB

    const __half* xwD = xWT + (size_t)(dir * 4 + bg) * ((size_t)TLEN * G4H * 16);
    __half* hD = hist + (size_t)(dir * BATCH + bg * 16) * TLEN * HSZ;

    // ---- load this wave's 64 Wh fp8 B-frags into VGPRs (once) ----
    unsigned long long wbf[8][8];
    {
        const unsigned long long* base = WhT8 + (size_t)(dir * 8 + w) * 4096;
#pragma unroll
        for (int gg = 0; gg < 8; ++gg)
#pragma unroll
            for (int ks = 0; ks < 8; ++ks)
                wbf[gg][ks] = base[(gg * 8 + ks) * 64 + lane];
    }

    for (int i = tid; i < 1024; i += 512) ((unsigned int*)h8)[i] = 0;

    float c[8];
#pragma unroll
    for (int i = 0; i < 8; ++i) c[i] = 0.0f;

    const int swzA = (l15 & 7) << 4;
    int xoff[8];
#pragma unroll
    for (int gg = 0; gg < 8; ++gg)
        xoff[gg] = ((gg >> 1) * 256 + w * 32 + (gg & 1) * 16 + l15) * 16 + lp * 4;

    f32x4 acc[8];
    u32x2 xwc[8], xwn[8];
    {
        const __half* p = xwD + (size_t)(dir ? (TLEN - 1) : 0) * (G4H * 16);
#pragma unroll
        for (int gg = 0; gg < 8; ++gg)
            xwc[gg] = *(const u32x2*)(p + xoff[gg]);
    }
    __syncthreads();

    for (int ts = 0; ts < TLEN; ++ts) {
        const int t = dir ? (TLEN - 1 - ts) : ts;

        // acc <- 64*xW(t)
#pragma unroll
        for (int gg = 0; gg < 8; ++gg) {
            const half2v lo = __builtin_bit_cast(half2v, xwc[gg][0]);
            const half2v hi = __builtin_bit_cast(half2v, xwc[gg][1]);
            f32x4 a; a[0]=(float)lo[0]; a[1]=(float)lo[1]; a[2]=(float)hi[0]; a[3]=(float)hi[1];
            acc[gg] = a;
        }

        // recurrent matmul: h8(t-1) [LDS] x wbf [VGPR] -> acc (adds 64*h.Wh)
#pragma unroll
        for (int ks = 0; ks < 8; ++ks) {
            const unsigned long long a =
                *(const unsigned long long*)(h8 + ((l15 * 256 + ks * 32 + lp * 8) ^ swzA));
#pragma unroll
            for (int gg = 0; gg < 8; ++gg)
                acc[gg] = __builtin_amdgcn_mfma_f32_16x16x32_fp8_fp8(
                    (long long)a, (long long)wbf[gg][ks], acc[gg], 0, 0, 0);
        }

        // prefetch next step's xW (consumed after the next barrier pair)
        {
            const int tn = dir ? (t > 0 ? t - 1 : 0) : (t < TLEN - 1 ? t + 1 : t);
            const __half* p = xwD + (size_t)tn * (G4H * 16);
#pragma unroll
            for (int gg = 0; gg < 8; ++gg)
                xwn[gg] = *(const u32x2*)(p + xoff[gg]);
        }

        __syncthreads();   // B1: all waves done reading h8(t-1)

        // cell update; write h(t) as fp8 (x8) and f16
#pragma unroll
        for (int ng = 0; ng < 2; ++ng) {
            const int u = w * 32 + ng * 16 + l15;
#pragma unroll
            for (int rr = 0; rr < 4; ++rr) {
                const float sc = 0.015625f;   // 1/64 descale
                const float ig = sigmoid_f(acc[    ng][rr] * sc);
                const float fg = sigmoid_f(acc[2 + ng][rr] * sc);
                const float gv = tanh_f   (acc[4 + ng][rr] * sc);
                const float og = sigmoid_f(acc[6 + ng][rr] * sc);
                float cc = c[ng * 4 + rr];
                cc = fg * cc + ig * gv;
                c[ng * 4 + rr] = cc;
                const float hv = og * tanh_f(cc);
                const int b = lp * 4 + rr;
                const int sw = (b & 7) << 4;
                *(ushort*)((char*)hstage + ((b * 512 + u * 2) ^ sw)) =
                    __half_as_ushort(__float2half(hv));
                h8[(b * 256 + u) ^ sw] = to_fp8(8.0f * hv);
            }
        }
        __syncthreads();   // B2: h(t) complete

        // spill h(t) f16 -> hist (coalesced; 512 thr x 16 B = 8 KB)
        {
            const int bl = tid >> 5, us = tid & 31;
            const uint4 v = *(const uint4*)((const char*)hstage +
                              ((bl * 512 + us * 16) ^ ((bl & 7) << 4)));
            *(uint4*)(hD + ((size_t)bl * TLEN + t) * HSZ + us * 8) = v;
        }

#pragma unroll
        for (int gg = 0; gg < 8; ++gg) xwc[gg] = xwn[gg];
    }
}

// ---------------------------------------------------------------------------
// K3: emissions em[b][t][k] = hf(b,t,:).fcW[k,0:256] + hb(b,t,:).fcW[k,256:512]
// hist layout: [dir][b][t][u]. grid = 64b x 8 tchunks, block 256.
// ---------------------------------------------------------------------------
__global__ __launch_bounds__(256)
void em_kernel(const __half* __restrict__ hist, const float* __restrict__ fcW,
               float* __restrict__ em) {
    const int b   = blockIdx.x >> 3;
    const int t0  = (blockIdx.x & 7) * 64;
    const int tid = threadIdx.x;

    __shared__ ushort hf[64][264];
    __shared__ ushort hb[64][264];
    __shared__ ushort fcs[32][520];

    for (int i = tid; i < 32 * 512; i += 256) {
        const int k = i >> 9, j = i & 511;
        fcs[k][j] = __half_as_ushort(__float2half(fcW[(size_t)k * HID + j]));
    }
    const __half* hfp = hist;
    const __half* hbp = hist + (size_t)BATCH * TLEN * HSZ;
    for (int i = tid; i < 64 * 32; i += 256) {
        const int row = i >> 5, seg = i & 31;
        const uint4 vf = *(const uint4*)(hfp + ((size_t)b * TLEN + t0 + row) * HSZ + seg*8);
        const uint4 vb = *(const uint4*)(hbp + ((size_t)b * TLEN + t0 + row) * HSZ + seg*8);
        *(uint4*)&hf[row][seg*8] = vf;
        *(uint4*)&hb[row][seg*8] = vb;
    }
    __syncthreads();

    const int tok = tid >> 2;     // 0..63
    const int kq  = tid & 3;      // k = kq*8 + kk
    float s[8] = {0,0,0,0,0,0,0,0};
    for (int j2 = 0; j2 < 128; ++j2) {
        const unsigned hfv = *(const unsigned*)&hf[tok][j2*2];
        const unsigned hbv = *(const unsigned*)&hb[tok][j2*2];
#pragma unroll
        for (int kk = 0; kk < 8; ++kk) {
            const int k = kq*8 + kk;
            s[kk] = fdot2f(hfv, *(const unsigned*)&fcs[k][j2*2], s[kk]);
            s[kk] = fdot2f(hbv, *(const unsigned*)&fcs[k][256 + j2*2], s[kk]);
        }
    }
    float* dst = em + ((size_t)b * TLEN + t0 + tok) * TAGS + kq*8;
#pragma unroll
    for (int kk = 0; kk < 8; ++kk) dst[kk] = s[kk];
}

// ---------------------------------------------------------------------------
// K4: CRF forward + gold score per batch row. grid 64, block 64.
// ---------------------------------------------------------------------------
__global__ void crf_kernel(const float* __restrict__ em, const float* __restrict__ fcb,
                           const float* __restrict__ trans, const float* __restrict__ startv,
                           const float* __restrict__ endv, const int* __restrict__ y,
                           float* __restrict__ partial) {
    const int b   = blockIdx.x;
    const int tid = threadIdx.x;

    __shared__ float alpha_s[TAGS];
    __shared__ float trans_s[TAGS][TAGS + 1];

    for (int i = tid; i < TAGS * TAGS; i += 64)
        trans_s[i >> 5][i & 31] = trans[i];

    const float* e = em + (size_t)b * TLEN * TAGS;

    if (tid < TAGS)
        alpha_s[tid] = startv[tid] + e[tid] + fcb[tid];
    __syncthreads();

    for (int t = 1; t < TLEN; ++t) {
        float anew = 0.0f;
        if (tid < TAGS) {
            float mx = -3.0e38f;
#pragma unroll
            for (int k2 = 0; k2 < TAGS; ++k2)
                mx = fmaxf(mx, alpha_s[k2] + trans_s[k2][tid]);
            float sm = 0.0f;
#pragma unroll
            for (int k2 = 0; k2 < TAGS; ++k2)
                sm += __expf(alpha_s[k2] + trans_s[k2][tid] - mx);
            anew = mx + __logf(sm) + e[t * TAGS + tid] + fcb[tid];
        }
        __syncthreads();
        if (tid < TAGS) alpha_s[tid] = anew;
        __syncthreads();
    }

    float v = (tid < TAGS) ? (alpha_s[tid] + endv[tid]) : -1.0e30f;
    float mx = v;
#pragma unroll
    for (int off = 32; off; off >>= 1) mx = fmaxf(mx, __shfl_xor(mx, off, 64));
    float ex = __expf(v - mx);
#pragma unroll
    for (int off = 32; off; off >>= 1) ex += __shfl_xor(ex, off, 64);
    const float logZ = mx + __logf(ex);

    const int* yb = y + (size_t)b * TLEN;
    float gsum = 0.0f;
    for (int t = tid; t < TLEN; t += 64) {
        const int yt = yb[t];
        gsum += e[t * TAGS + yt] + fcb[yt];
    }
    for (int t = tid; t < TLEN - 1; t += 64)
        gsum += trans[yb[t] * TAGS + yb[t + 1]];
#pragma unroll
    for (int off = 32; off; off >>= 1) gsum += __shfl_xor(gsum, off, 64);

    if (tid == 0) {
        const float num = startv[yb[0]] + gsum + endv[yb[TLEN - 1]];
        partial[b] = logZ - num;
    }
}

// ---------------------------------------------------------------------------
// K5: final mean
// ---------------------------------------------------------------------------
__global__ void reduce_kernel(const float* __restrict__ partial, float* __restrict__ out) {
    float v = partial[threadIdx.x];
#pragma unroll
    for (int off = 32; off; off >>= 1) v += __shfl_xor(v, off, 64);
    if (threadIdx.x == 0) out[0] = v * (1.0f / BATCH);
}

// ---------------------------------------------------------------------------
extern "C" void kernel_launch(void* const* d_in, const int* in_sizes, int n_in,
                              void* d_out, int out_size, void* d_ws, size_t ws_size,
                              hipStream_t stream) {
    (void)in_sizes; (void)n_in; (void)out_size; (void)ws_size;

    const int*   X      = (const int*)  d_in[0];
    const int*   y      = (const int*)  d_in[1];
    const float* embed  = (const float*)d_in[2];
    const float* Wi_f   = (const float*)d_in[3];
    const float* Wh_f   = (const float*)d_in[4];
    const float* b_f    = (const float*)d_in[5];
    const float* Wi_b   = (const float*)d_in[6];
    const float* Wh_b   = (const float*)d_in[7];
    const float* b_b    = (const float*)d_in[8];
    const float* fcW    = (const float*)d_in[9];
    const float* fcb    = (const float*)d_in[10];
    const float* trans  = (const float*)d_in[11];
    const float* startv = (const float*)d_in[12];
    const float* endv   = (const float*)d_in[13];
    float* out = (float*)d_out;

    // workspace layout (em aliases xWT: xWT is dead once lstm_kernel finishes)
    char* ws = (char*)d_ws;
    __half* xWT  = (__half*)(ws);                        // [2][4][512][1024][16] f16 = 134217728 B
    float*  em   = (float*) (ws);                        // alias: [64][512][32] f32 = 4194304 B
    __half* hist = (__half*)(ws + 134217728);            // [2][64][512][256] f16 = 33554432 B
    unsigned long long* WhT8 = (unsigned long long*)(ws + 167772160);  // fp8 B-frag image, 524288 B
    float*  prt  = (float*) (ws + 168820736);            // 256 B

    whimg_kernel<<<256, 256, 0, stream>>>(Wh_f, Wh_b, WhT8);

    dim3 ggrid(TLEN, G4H / 64, 2);
    gemm_xwt_kernel<<<ggrid, 256, 0, stream>>>(X, embed, Wi_f, b_f, Wi_b, b_b, xWT);

    dim3 lgrid(4, 2);
    lstm_kernel<<<lgrid, 512, 0, stream>>>(xWT, WhT8, hist);

    em_kernel<<<BATCH * 8, 256, 0, stream>>>(hist, fcW, em);

    crf_kernel<<<BATCH, 64, 0, stream>>>(em, fcb, trans, startv, endv, y, prt);

    reduce_kernel<<<1, 64, 0, stream>>>(prt, out);
}

// Round 8
// 2479.350 us; speedup vs baseline: 3.1970x; 1.2881x over previous
//
#include <hip/hip_runtime.h>
#include <hip/hip_fp16.h>
#include <hip/hip_fp8.h>
#include <stdint.h>

// Problem constants (NamedEntityRecognitionModel)
#define TAGS  32
#define EMB   256
#define HID   512
#define HSZ   256        // per-direction hidden
#define G4H   1024       // 4*HSZ
#define BATCH 64
#define TLEN  512

typedef _Float16 half8  __attribute__((ext_vector_type(8)));
typedef _Float16 half2v __attribute__((ext_vector_type(2)));
typedef float    f32x4  __attribute__((ext_vector_type(4)));
typedef unsigned int u32x2 __attribute__((ext_vector_type(2)));

#if defined(__has_builtin)
#if __has_builtin(__builtin_amdgcn_fdot2)
#define HAVE_FDOT2 1
#endif
#if __has_builtin(__builtin_amdgcn_cvt_pk_fp8_f32)
#define HAVE_CVTFP8 1
#endif
#endif

__device__ __forceinline__ float fdot2f(unsigned a, unsigned b, float c) {
    half2v ha = __builtin_bit_cast(half2v, a);
    half2v hb = __builtin_bit_cast(half2v, b);
#ifdef HAVE_FDOT2
    return __builtin_amdgcn_fdot2(ha, hb, c, false);
#else
    return c + (float)ha[0]*(float)hb[0] + (float)ha[1]*(float)hb[1];
#endif
}
__device__ __forceinline__ float sigmoid_f(float x){ return 1.0f/(1.0f+__expf(-x)); }
__device__ __forceinline__ float tanh_f(float x){ return 1.0f - 2.0f/(__expf(2.0f*x)+1.0f); }

// float -> OCP e4m3fn byte (HW convert when available)
__device__ __forceinline__ unsigned char to_fp8(float x) {
#ifdef HAVE_CVTFP8
    return (unsigned char)(__builtin_amdgcn_cvt_pk_fp8_f32(x, x, 0, false) & 0xff);
#else
    __hip_fp8_e4m3 q(x);
    return (unsigned char)q.__x;
#endif
}

// ---------------------------------------------------------------------------
// K0a: fp8 MFMA B-fragment image of Wh, scaled by 8.
// Slot: [dir][w 8][gg 8][ks 8][lane 64] x 8 bytes:
//   n = (gg>>1)*256 + w*32 + (gg&1)*16 + (lane&15), k = ks*32 + (lane>>4)*8 + e
// ---------------------------------------------------------------------------
__global__ __launch_bounds__(256)
void whimg_kernel(const float* __restrict__ WhF, const float* __restrict__ WhB,
                  unsigned long long* __restrict__ WhT8) {
    const int slot = blockIdx.x * 256 + threadIdx.x;   // 0..65535
    const int dir = slot >> 15, r = slot & 32767;
    const int lane = r & 63;
    const int ks = (r >> 6) & 7;
    const int gg = (r >> 9) & 7;
    const int w  = (r >> 12) & 7;
    const int n = (gg >> 1) * 256 + w * 32 + (gg & 1) * 16 + (lane & 15);
    const int k = ks * 32 + (lane >> 4) * 8;
    const float* src = (dir ? WhB : WhF) + (size_t)n * HSZ + k;
    unsigned long long v = 0;
#pragma unroll
    for (int e = 0; e < 8; ++e)
        v |= (unsigned long long)to_fp8(8.0f * src[e]) << (8 * e);
    WhT8[slot] = v;
}

// ---------------------------------------------------------------------------
// K0b: f16 MFMA B-fragment image of Wi (unscaled).
// Slot: [dir][nt 64][ks 8][lane 64] x 8 f16:
//   n = nt*16 + (lane&15), k = ks*32 + (lane>>4)*8 + e
// ---------------------------------------------------------------------------
__global__ __launch_bounds__(256)
void wiimg_kernel(const float* __restrict__ WiF, const float* __restrict__ WiB,
                  half8* __restrict__ WiT) {
    const int slot = blockIdx.x * 256 + threadIdx.x;   // 0..65535
    const int lane = slot & 63;
    const int ks = (slot >> 6) & 7;
    const int nt = (slot >> 9) & 63;
    const int dir = slot >> 15;
    const int n = nt * 16 + (lane & 15);
    const int k = ks * 32 + (lane >> 4) * 8;
    const float* src = (dir ? WiB : WiF) + (size_t)n * EMB + k;
    half8 hv;
#pragma unroll
    for (int e = 0; e < 8; ++e) hv[e] = (_Float16)src[e];
    WiT[slot] = hv;
}

// ---------------------------------------------------------------------------
// K1: MFMA input GEMM. xWT[dir][bg][t][n 1024][16 b] = 64*(embed[X[b][t]].Wi[n] + bias[n])
// grid (512 t, 2 dir), block 256 (4 waves). A (64 embed rows) gathered to LDS
// then hoisted to VGPR A-frags; B streamed from the WiT L2-hot image.
// Wave w owns n in [w*256, w*256+256) = 16 nt tiles.
// ---------------------------------------------------------------------------
__global__ __launch_bounds__(256, 2)
void gemm_xwt_kernel(const int* __restrict__ X, const float* __restrict__ embed,
                     const half8* __restrict__ WiT, const float* __restrict__ bF,
                     const float* __restrict__ bB, __half* __restrict__ xWT) {
    const int t   = blockIdx.x;
    const int dir = blockIdx.y;
    const int tid = threadIdx.x;
    const int lane = tid & 63;
    const int w    = tid >> 6;
    const int l15  = lane & 15;
    const int lp   = lane >> 4;
    const float* bias = dir ? bB : bF;

    __shared__ ushort A[4 * 8 * 64 * 8];   // [mt][ks][lane][8e] f16 = 32 KB

    // ---- stage A: row b = tid>>2, k-range (tid&3)*64..+64 ----
    {
        const int b = tid >> 2, part = tid & 3;
        const int erow = X[b * TLEN + t];
        const float* src = embed + (size_t)erow * EMB + part * 64;
        const int mt = b >> 4, bl = b & 15;
#pragma unroll
        for (int q = 0; q < 2; ++q) {
            const int ks = part * 2 + q;
#pragma unroll
            for (int lpp = 0; lpp < 4; ++lpp) {
                const float4 x0 = *(const float4*)(src + q * 32 + lpp * 8);
                const float4 x1 = *(const float4*)(src + q * 32 + lpp * 8 + 4);
                half8 hv;
                hv[0]=(_Float16)x0.x; hv[1]=(_Float16)x0.y; hv[2]=(_Float16)x0.z; hv[3]=(_Float16)x0.w;
                hv[4]=(_Float16)x1.x; hv[5]=(_Float16)x1.y; hv[6]=(_Float16)x1.z; hv[7]=(_Float16)x1.w;
                *(half8*)&A[(((mt * 8 + ks) * 64) + lpp * 16 + bl) * 8] = hv;
            }
        }
    }
    __syncthreads();

    // ---- hoist A-frags to VGPRs: [mt 4][ks 8] ----
    half8 afr[4][8];
#pragma unroll
    for (int mt = 0; mt < 4; ++mt)
#pragma unroll
        for (int ks = 0; ks < 8; ++ks)
            afr[mt][ks] = *(const half8*)&A[(((mt * 8 + ks) * 64) + lane) * 8];

    const half8* Bw = WiT + (size_t)(dir * 64 + w * 16) * 8 * 64;

    half8 bcur[8], bnxt[8];
#pragma unroll
    for (int ks = 0; ks < 8; ++ks) bcur[ks] = Bw[(size_t)ks * 64 + lane];

#pragma unroll
    for (int j = 0; j < 16; ++j) {
        if (j < 15) {
#pragma unroll
            for (int ks = 0; ks < 8; ++ks)
                bnxt[ks] = Bw[((size_t)(j + 1) * 8 + ks) * 64 + lane];
        }
        f32x4 acc4[4] = {};
#pragma unroll
        for (int ks = 0; ks < 8; ++ks)
#pragma unroll
            for (int mt = 0; mt < 4; ++mt)
                acc4[mt] = __builtin_amdgcn_mfma_f32_16x16x32_f16(afr[mt][ks], bcur[ks], acc4[mt], 0, 0, 0);

        const int nt = w * 16 + j;
        const float bs = bias[nt * 16 + l15];
#pragma unroll
        for (int mt = 0; mt < 4; ++mt) {
            unsigned long long pk = 0;
#pragma unroll
            for (int rr = 0; rr < 4; ++rr) {
                const __half hh = __float2half(64.0f * (acc4[mt][rr] + bs));
                pk |= (unsigned long long)__half_as_ushort(hh) << (16 * rr);
            }
            __half* dst = xWT + ((size_t)((dir * 4 + mt) * TLEN + t)) * (G4H * 16)
                        + (size_t)(nt * 16 + l15) * 16 + lp * 4;
            *(unsigned long long*)dst = pk;
        }
#pragma unroll
        for (int ks = 0; ks < 8; ++ks) bcur[ks] = bnxt[ks];
    }
}

// ---------------------------------------------------------------------------
// K2: batch-split LSTM, Wh fp8 FORCED VGPR-resident, zero inter-block sync.
// grid (4 bg, 2 dir), block 512 (8 waves -> 2/SIMD). Wave w: units [32w,32w+32).
// ---------------------------------------------------------------------------
__global__ __launch_bounds__(512, 2)
void lstm_kernel(const __half* __restrict__ xWT,
                 const unsigned long long* __restrict__ WhT8,
                 __half* __restrict__ hist) {
    const int bg  = blockIdx.x;       // 0..3
    const int dir = blockIdx.y;       // 0..1
    const int tid = threadIdx.x;
    const int lane = tid & 63;
    const int w    = tid >> 6;        // wave 0..7
    const int l15  = lane & 15;
    const int lp   = lane >> 4;

    __shared__ unsigned char h8[16 * 256];   // fp8(8*h): [b][u], XOR-swizzled, 4 KB
    __shared__ ushort hstage[16 * 256];      // f16 h:    [b][u], XOR-swizzled, 8 KB

    const __half* xwD = xWT + (size_t)(dir * 4 + bg) * ((size_t)TLEN * G4H * 16);
    __half* hD = hist + (size_t)(dir * BATCH + bg * 16) * TLEN * HSZ;

    // ---- load this wave's 64 Wh fp8 B-frags into VGPRs; force residency ----
    unsigned long long wbf[8][8];
    {
        const unsigned long long* base = WhT8 + (size_t)(dir * 8 + w) * 4096;
#pragma unroll
        for (int gg = 0; gg < 8; ++gg)
#pragma unroll
            for (int ks = 0; ks < 8; ++ks) {
                unsigned long long v = base[(gg * 8 + ks) * 64 + lane];
                unsigned lo = (unsigned)v, hi = (unsigned)(v >> 32);
                asm volatile("" : "+v"(lo), "+v"(hi));   // opaque: no remat
                wbf[gg][ks] = ((unsigned long long)hi << 32) | lo;
            }
    }

    for (int i = tid; i < 1024; i += 512) ((unsigned int*)h8)[i] = 0;

    float c[8];
#pragma unroll
    for (int i = 0; i < 8; ++i) c[i] = 0.0f;

    const int swzA = (l15 & 7) << 4;
    int xoff[8];
#pragma unroll
    for (int gg = 0; gg < 8; ++gg)
        xoff[gg] = ((gg >> 1) * 256 + w * 32 + (gg & 1) * 16 + l15) * 16 + lp * 4;

    f32x4 acc[8];
    u32x2 xwc[8], xwn[8];
    {
        const __half* p = xwD + (size_t)(dir ? (TLEN - 1) : 0) * (G4H * 16);
#pragma unroll
        for (int gg = 0; gg < 8; ++gg)
            xwc[gg] = *(const u32x2*)(p + xoff[gg]);
    }
    __syncthreads();

    for (int ts = 0; ts < TLEN; ++ts) {
        const int t = dir ? (TLEN - 1 - ts) : ts;

        // acc <- 64*xW(t)
#pragma unroll
        for (int gg = 0; gg < 8; ++gg) {
            const half2v lo = __builtin_bit_cast(half2v, xwc[gg][0]);
            const half2v hi = __builtin_bit_cast(half2v, xwc[gg][1]);
            f32x4 a; a[0]=(float)lo[0]; a[1]=(float)lo[1]; a[2]=(float)hi[0]; a[3]=(float)hi[1];
            acc[gg] = a;
        }

        // recurrent matmul: h8(t-1) [LDS] x wbf [VGPR] -> acc (adds 64*h.Wh)
#pragma unroll
        for (int ks = 0; ks < 8; ++ks) {
            const unsigned long long a =
                *(const unsigned long long*)(h8 + ((l15 * 256 + ks * 32 + lp * 8) ^ swzA));
#pragma unroll
            for (int gg = 0; gg < 8; ++gg)
                acc[gg] = __builtin_amdgcn_mfma_f32_16x16x32_fp8_fp8(
                    (long long)a, (long long)wbf[gg][ks], acc[gg], 0, 0, 0);
        }

        // prefetch next step's xW (consumed after the next barrier pair)
        {
            const int tn = dir ? (t > 0 ? t - 1 : 0) : (t < TLEN - 1 ? t + 1 : t);
            const __half* p = xwD + (size_t)tn * (G4H * 16);
#pragma unroll
            for (int gg = 0; gg < 8; ++gg)
                xwn[gg] = *(const u32x2*)(p + xoff[gg]);
        }

        __syncthreads();   // B1: all waves done reading h8(t-1)

        // cell update; write h(t) as fp8 (x8) and f16
#pragma unroll
        for (int ng = 0; ng < 2; ++ng) {
            const int u = w * 32 + ng * 16 + l15;
#pragma unroll
            for (int rr = 0; rr < 4; ++rr) {
                const float sc = 0.015625f;   // 1/64 descale
                const float ig = sigmoid_f(acc[    ng][rr] * sc);
                const float fg = sigmoid_f(acc[2 + ng][rr] * sc);
                const float gv = tanh_f   (acc[4 + ng][rr] * sc);
                const float og = sigmoid_f(acc[6 + ng][rr] * sc);
                float cc = c[ng * 4 + rr];
                cc = fg * cc + ig * gv;
                c[ng * 4 + rr] = cc;
                const float hv = og * tanh_f(cc);
                const int b = lp * 4 + rr;
                const int sw = (b & 7) << 4;
                *(ushort*)((char*)hstage + ((b * 512 + u * 2) ^ sw)) =
                    __half_as_ushort(__float2half(hv));
                h8[(b * 256 + u) ^ sw] = to_fp8(8.0f * hv);
            }
        }
        __syncthreads();   // B2: h(t) complete

        // spill h(t) f16 -> hist (coalesced; 512 thr x 16 B = 8 KB)
        {
            const int bl = tid >> 5, us = tid & 31;
            const uint4 v = *(const uint4*)((const char*)hstage +
                              ((bl * 512 + us * 16) ^ ((bl & 7) << 4)));
            *(uint4*)(hD + ((size_t)bl * TLEN + t) * HSZ + us * 8) = v;
        }

#pragma unroll
        for (int gg = 0; gg < 8; ++gg) xwc[gg] = xwn[gg];
    }
}

// ---------------------------------------------------------------------------
// K3: emissions em[b][t][k] = hf(b,t,:).fcW[k,0:256] + hb(b,t,:).fcW[k,256:512]
// hist layout: [dir][b][t][u]. grid = 64b x 8 tchunks, block 256.
// ---------------------------------------------------------------------------
__global__ __launch_bounds__(256)
void em_kernel(const __half* __restrict__ hist, const float* __restrict__ fcW,
               float* __restrict__ em) {
    const int b   = blockIdx.x >> 3;
    const int t0  = (blockIdx.x & 7) * 64;
    const int tid = threadIdx.x;

    __shared__ ushort hf[64][264];
    __shared__ ushort hb[64][264];
    __shared__ ushort fcs[32][520];

    for (int i = tid; i < 32 * 512; i += 256) {
        const int k = i >> 9, j = i & 511;
        fcs[k][j] = __half_as_ushort(__float2half(fcW[(size_t)k * HID + j]));
    }
    const __half* hfp = hist;
    const __half* hbp = hist + (size_t)BATCH * TLEN * HSZ;
    for (int i = tid; i < 64 * 32; i += 256) {
        const int row = i >> 5, seg = i & 31;
        const uint4 vf = *(const uint4*)(hfp + ((size_t)b * TLEN + t0 + row) * HSZ + seg*8);
        const uint4 vb = *(const uint4*)(hbp + ((size_t)b * TLEN + t0 + row) * HSZ + seg*8);
        *(uint4*)&hf[row][seg*8] = vf;
        *(uint4*)&hb[row][seg*8] = vb;
    }
    __syncthreads();

    const int tok = tid >> 2;     // 0..63
    const int kq  = tid & 3;      // k = kq*8 + kk
    float s[8] = {0,0,0,0,0,0,0,0};
    for (int j2 = 0; j2 < 128; ++j2) {
        const unsigned hfv = *(const unsigned*)&hf[tok][j2*2];
        const unsigned hbv = *(const unsigned*)&hb[tok][j2*2];
#pragma unroll
        for (int kk = 0; kk < 8; ++kk) {
            const int k = kq*8 + kk;
            s[kk] = fdot2f(hfv, *(const unsigned*)&fcs[k][j2*2], s[kk]);
            s[kk] = fdot2f(hbv, *(const unsigned*)&fcs[k][256 + j2*2], s[kk]);
        }
    }
    float* dst = em + ((size_t)b * TLEN + t0 + tok) * TAGS + kq*8;
#pragma unroll
    for (int kk = 0; kk < 8; ++kk) dst[kk] = s[kk];
}

// ---------------------------------------------------------------------------
// K4: CRF forward + gold score per batch row. grid 64, block 64.
// ---------------------------------------------------------------------------
__global__ void crf_kernel(const float* __restrict__ em, const float* __restrict__ fcb,
                           const float* __restrict__ trans, const float* __restrict__ startv,
                           const float* __restrict__ endv, const int* __restrict__ y,
                           float* __restrict__ partial) {
    const int b   = blockIdx.x;
    const int tid = threadIdx.x;

    __shared__ float alpha_s[TAGS];
    __shared__ float trans_s[TAGS][TAGS + 1];

    for (int i = tid; i < TAGS * TAGS; i += 64)
        trans_s[i >> 5][i & 31] = trans[i];

    const float* e = em + (size_t)b * TLEN * TAGS;

    if (tid < TAGS)
        alpha_s[tid] = startv[tid] + e[tid] + fcb[tid];
    __syncthreads();

    for (int t = 1; t < TLEN; ++t) {
        float anew = 0.0f;
        if (tid < TAGS) {
            float mx = -3.0e38f;
#pragma unroll
            for (int k2 = 0; k2 < TAGS; ++k2)
                mx = fmaxf(mx, alpha_s[k2] + trans_s[k2][tid]);
            float sm = 0.0f;
#pragma unroll
            for (int k2 = 0; k2 < TAGS; ++k2)
                sm += __expf(alpha_s[k2] + trans_s[k2][tid] - mx);
            anew = mx + __logf(sm) + e[t * TAGS + tid] + fcb[tid];
        }
        __syncthreads();
        if (tid < TAGS) alpha_s[tid] = anew;
        __syncthreads();
    }

    float v = (tid < TAGS) ? (alpha_s[tid] + endv[tid]) : -1.0e30f;
    float mx = v;
#pragma unroll
    for (int off = 32; off; off >>= 1) mx = fmaxf(mx, __shfl_xor(mx, off, 64));
    float ex = __expf(v - mx);
#pragma unroll
    for (int off = 32; off; off >>= 1) ex += __shfl_xor(ex, off, 64);
    const float logZ = mx + __logf(ex);

    const int* yb = y + (size_t)b * TLEN;
    float gsum = 0.0f;
    for (int t = tid; t < TLEN; t += 64) {
        const int yt = yb[t];
        gsum += e[t * TAGS + yt] + fcb[yt];
    }
    for (int t = tid; t < TLEN - 1; t += 64)
        gsum += trans[yb[t] * TAGS + yb[t + 1]];
#pragma unroll
    for (int off = 32; off; off >>= 1) gsum += __shfl_xor(gsum, off, 64);

    if (tid == 0) {
        const float num = startv[yb[0]] + gsum + endv[yb[TLEN - 1]];
        partial[b] = logZ - num;
    }
}

// ---------------------------------------------------------------------------
// K5: final mean
// ---------------------------------------------------------------------------
__global__ void reduce_kernel(const float* __restrict__ partial, float* __restrict__ out) {
    float v = partial[threadIdx.x];
#pragma unroll
    for (int off = 32; off; off >>= 1) v += __shfl_xor(v, off, 64);
    if (threadIdx.x == 0) out[0] = v * (1.0f / BATCH);
}

// ---------------------------------------------------------------------------
extern "C" void kernel_launch(void* const* d_in, const int* in_sizes, int n_in,
                              void* d_out, int out_size, void* d_ws, size_t ws_size,
                              hipStream_t stream) {
    (void)in_sizes; (void)n_in; (void)out_size; (void)ws_size;

    const int*   X      = (const int*)  d_in[0];
    const int*   y      = (const int*)  d_in[1];
    const float* embed  = (const float*)d_in[2];
    const float* Wi_f   = (const float*)d_in[3];
    const float* Wh_f   = (const float*)d_in[4];
    const float* b_f    = (const float*)d_in[5];
    const float* Wi_b   = (const float*)d_in[6];
    const float* Wh_b   = (const float*)d_in[7];
    const float* b_b    = (const float*)d_in[8];
    const float* fcW    = (const float*)d_in[9];
    const float* fcb    = (const float*)d_in[10];
    const float* trans  = (const float*)d_in[11];
    const float* startv = (const float*)d_in[12];
    const float* endv   = (const float*)d_in[13];
    float* out = (float*)d_out;

    // workspace layout (em aliases xWT: xWT is dead once lstm_kernel finishes)
    char* ws = (char*)d_ws;
    __half* xWT  = (__half*)(ws);                        // [2][4][512][1024][16] f16 = 134217728 B
    float*  em   = (float*) (ws);                        // alias: [64][512][32] f32 = 4194304 B
    __half* hist = (__half*)(ws + 134217728);            // [2][64][512][256] f16 = 33554432 B
    unsigned long long* WhT8 = (unsigned long long*)(ws + 167772160);  // fp8 Wh image, 524288 B
    half8*  WiT  = (half8*) (ws + 168296448);            // f16 Wi image, 1048576 B
    float*  prt  = (float*) (ws + 169345024);            // 256 B

    whimg_kernel<<<256, 256, 0, stream>>>(Wh_f, Wh_b, WhT8);
    wiimg_kernel<<<256, 256, 0, stream>>>(Wi_f, Wi_b, WiT);

    dim3 ggrid(TLEN, 2);
    gemm_xwt_kernel<<<ggrid, 256, 0, stream>>>(X, embed, WiT, b_f, b_b, xWT);

    dim3 lgrid(4, 2);
    lstm_kernel<<<lgrid, 512, 0, stream>>>(xWT, WhT8, hist);

    em_kernel<<<BATCH * 8, 256, 0, stream>>>(hist, fcW, em);

    crf_kernel<<<BATCH, 64, 0, stream>>>(em, fcb, trans, startv, endv, y, prt);

    reduce_kernel<<<1, 64, 0, stream>>>(prt, out);
}